// Round 10
// baseline (662.315 us; speedup 1.0000x reference)
//
#include <hip/hip_runtime.h>
#include <math.h>

#define CIN 128
#define HD  96
#define SP  3136   // 56*56
#define ROW 56
#define SLAB 1568  // 28*56

// ---------------- Kernel A: P[e][ci][co] = sum_c Wo[co][e*24+c]*Wp[e*24+c][ci]; obp ----------------
__global__ __launch_bounds__(256) void pe_k(
    const float* __restrict__ Wo, const float* __restrict__ Wp,
    const float* __restrict__ bp, float* __restrict__ P, float* __restrict__ obp)
{
  const int e = blockIdx.x;
  __shared__ float ws[24][128];
  const int tid = threadIdx.x;
  for (int i = tid; i < 24 * 128; i += 256)
    ws[i >> 7][i & 127] = Wp[(size_t)(e * 24 + (i >> 7)) * CIN + (i & 127)];
  __syncthreads();
  const int co = tid & 127;
  const int cig = tid >> 7;
  float wo_r[24];
  #pragma unroll
  for (int c = 0; c < 24; ++c) wo_r[c] = Wo[(size_t)co * HD + e * 24 + c];
  for (int ci = cig * 64; ci < cig * 64 + 64; ++ci) {
    float s = 0.f;
    #pragma unroll
    for (int c = 0; c < 24; ++c) s = fmaf(wo_r[c], ws[c][ci], s);
    P[((size_t)e * 128 + ci) * 128 + co] = s;
  }
  if (cig == 0) {
    float s = 0.f;
    #pragma unroll
    for (int c = 0; c < 24; ++c) s = fmaf(wo_r[c], bp[e * 24 + c], s);
    obp[e * 128 + co] = s;
  }
}

// ---------------- Kernel 1: q-only 1x1 conv (R4 structure, 96 outputs, 128 threads) ----------------
__global__ __launch_bounds__(128) void q_conv(
    const float* __restrict__ x, const float* __restrict__ Wc,
    const float* __restrict__ bc, float* __restrict__ qbuf)
{
  const int st = blockIdx.x % 49;
  const int b  = blockIdx.x / 49;
  const float* xb = x + (size_t)b * CIN * SP + st * 64;

  __shared__ float xs[32][64];      // 8 KB
  __shared__ float wl[32][100];     // 12.5 KB (96 + pad)

  const int tid = threadIdx.x;
  const int og = tid >> 4;          // 0..7 -> o0 = og*12
  const int sg = tid & 15;          // 0..15 -> s0 = sg*4

  float acc[12][4];
  #pragma unroll
  for (int i = 0; i < 12; ++i) { acc[i][0]=0.f; acc[i][1]=0.f; acc[i][2]=0.f; acc[i][3]=0.f; }

  for (int kt = 0; kt < 4; ++kt) {
    __syncthreads();
    #pragma unroll
    for (int r = 0; r < 4; ++r) {
      int i = tid + r * 128;
      int cc = i >> 4, s4 = i & 15;
      float4 v = *reinterpret_cast<const float4*>(xb + (size_t)(kt*32 + cc) * SP + s4*4);
      *reinterpret_cast<float4*>(&xs[cc][s4*4]) = v;
    }
    #pragma unroll
    for (int r = 0; r < 6; ++r) {
      int i = tid + r * 128;        // 0..767: 96 rows x 8 float4
      int o  = i >> 3, c4 = i & 7;
      float4 wv = *reinterpret_cast<const float4*>(Wc + (size_t)o * CIN + kt*32 + c4*4);
      wl[c4*4+0][o] = wv.x; wl[c4*4+1][o] = wv.y;
      wl[c4*4+2][o] = wv.z; wl[c4*4+3][o] = wv.w;
    }
    __syncthreads();
    #pragma unroll
    for (int cc = 0; cc < 32; ++cc) {
      float xv[4];
      *reinterpret_cast<float4*>(xv) = *reinterpret_cast<const float4*>(&xs[cc][sg*4]);
      float wv[12];
      *reinterpret_cast<float4*>(wv + 0) = *reinterpret_cast<const float4*>(&wl[cc][og*12 + 0]);
      *reinterpret_cast<float4*>(wv + 4) = *reinterpret_cast<const float4*>(&wl[cc][og*12 + 4]);
      *reinterpret_cast<float4*>(wv + 8) = *reinterpret_cast<const float4*>(&wl[cc][og*12 + 8]);
      #pragma unroll
      for (int i = 0; i < 12; ++i)
        #pragma unroll
        for (int j = 0; j < 4; ++j)
          acc[i][j] = fmaf(wv[i], xv[j], acc[i][j]);
    }
  }
  #pragma unroll
  for (int i = 0; i < 12; ++i) {
    const int o = og * 12 + i;
    const float bias = bc[o];
    float4 v;
    v.x = acc[i][0] + bias; v.y = acc[i][1] + bias;
    v.z = acc[i][2] + bias; v.w = acc[i][3] + bias;
    *reinterpret_cast<float4*>(qbuf + ((size_t)b*96 + o) * SP + st*64 + sg*4) = v;
  }
}

// ---------------- Kernel 2: clustering per (b,e,f1); exports s/g/lists/dn into dead q ----------------
__global__ __launch_bounds__(512, 4) void cluster_k(
    float* qbuf, const float* __restrict__ alpha_p, const float* __restrict__ beta_p)
{
  const int blk = blockIdx.x;              // (b*4+e)*2 + f1
  const int f1  = blk & 1;
  const int be  = blk >> 1;
  const size_t base = (size_t)be * 24 * SP + (size_t)(f1 * 28) * ROW;
  float* qp = qbuf + base;

  __shared__ double cnd[24][8];
  __shared__ float  sbest[SLAB];
  __shared__ unsigned char ibest[SLAB];    // g = f2*4 + argmax (0..7)
  __shared__ unsigned short nlist[SLAB];
  __shared__ int   cnts[8];
  __shared__ int   starts[9];
  __shared__ float dnl[8];

  const int tid  = threadIdx.x;
  const int wid  = tid >> 6;
  const int lane = tid & 63;

  // phase 1: pooled q centers (wave per channel, 8 masked bins)
  for (int c = wid; c < 24; c += 8) {
    const float* src = qp + (size_t)c * SP;
    double b0=0,b1=0,b2=0,b3=0,b4=0,b5=0,b6=0,b7=0;
    for (int n = lane; n < SLAB; n += 64) {
      const int w = n / 56, h = n - w * 56;
      const int hf = (h >= 28) ? (h - 28) : h;
      const int g  = ((h >= 28) ? 4 : 0) + ((w >= 14) ? 2 : 0) + ((hf >= 14) ? 1 : 0);
      const double val = (double)src[n];
      b0 += (g==0)?val:0.0; b1 += (g==1)?val:0.0;
      b2 += (g==2)?val:0.0; b3 += (g==3)?val:0.0;
      b4 += (g==4)?val:0.0; b5 += (g==5)?val:0.0;
      b6 += (g==6)?val:0.0; b7 += (g==7)?val:0.0;
    }
    #pragma unroll
    for (int m = 32; m >= 1; m >>= 1) {
      b0 += __shfl_xor(b0,m); b1 += __shfl_xor(b1,m);
      b2 += __shfl_xor(b2,m); b3 += __shfl_xor(b3,m);
      b4 += __shfl_xor(b4,m); b5 += __shfl_xor(b5,m);
      b6 += __shfl_xor(b6,m); b7 += __shfl_xor(b7,m);
    }
    if (lane == 0) {
      cnd[c][0]=b0*(1.0/196.0); cnd[c][1]=b1*(1.0/196.0);
      cnd[c][2]=b2*(1.0/196.0); cnd[c][3]=b3*(1.0/196.0);
      cnd[c][4]=b4*(1.0/196.0); cnd[c][5]=b5*(1.0/196.0);
      cnd[c][6]=b6*(1.0/196.0); cnd[c][7]=b7*(1.0/196.0);
    }
  }
  __syncthreads();
  if (tid < 8) {
    double s = 0.0;
    #pragma unroll
    for (int c = 0; c < 24; ++c) { double t = cnd[c][tid]; s += t * t; }
    const double inv = 1.0 / fmax(sqrt(s), 1e-12);
    #pragma unroll
    for (int c = 0; c < 24; ++c) cnd[c][tid] *= inv;
  }
  __syncthreads();

  const double alpha = (double)alpha_p[0];
  const double beta  = (double)beta_p[0];

  // phase 2: fp64 z dots, strict-first argmax, one sigmoid
  for (int n0 = tid; n0 < SLAB; n0 += 512) {
    const int h  = n0 % 56;
    const int gb = (h >= 28) ? 4 : 0;
    double z0=0,z1=0,z2=0,z3=0,nrm=0;
    for (int c = 0; c < 24; ++c) {
      const double qv = (double)qp[(size_t)c * SP + n0];
      z0 += cnd[c][gb+0]*qv; z1 += cnd[c][gb+1]*qv;
      z2 += cnd[c][gb+2]*qv; z3 += cnd[c][gb+3]*qv;
      nrm += qv*qv;
    }
    const double inv = 1.0 / fmax(sqrt(nrm), 1e-12);
    const double v0 = beta + alpha * (z0 * inv);
    const double v1 = beta + alpha * (z1 * inv);
    const double v2 = beta + alpha * (z2 * inv);
    const double v3 = beta + alpha * (z3 * inv);
    double zb = v0; int bi = 0;
    if (v1 > zb) { zb = v1; bi = 1; }
    if (v2 > zb) { zb = v2; bi = 2; }
    if (v3 > zb) { zb = v3; bi = 3; }
    sbest[n0] = (float)(1.0 / (1.0 + exp(-zb)));
    ibest[n0] = (unsigned char)(gb + bi);
  }
  __syncthreads();

  // phase 3a: per-bin counts + dn (wave k handles bin k)
  if (wid < 8) {
    float dn = 0.f; int cnt = 0;
    for (int ch = 0; ch < 25; ++ch) {
      const int n = ch * 64 + lane;
      const bool p = (n < SLAB) && (ibest[n] == (unsigned char)wid);
      const unsigned long long m = __ballot(p);
      cnt += (int)__popcll(m);
      dn += p ? sbest[n] : 0.f;
    }
    #pragma unroll
    for (int m = 32; m >= 1; m >>= 1) dn += __shfl_xor(dn, m);
    if (lane == 0) { cnts[wid] = cnt; dnl[wid] = dn; }
  }
  __syncthreads();
  if (tid == 0) {
    int a = 0;
    #pragma unroll
    for (int k = 0; k < 8; ++k) { starts[k] = a; a += cnts[k]; }
    starts[8] = a;
  }
  __syncthreads();
  // phase 3b: deterministic ballot-compacted pixel lists (ascending n per bin)
  if (wid < 8) {
    int off = starts[wid];
    for (int ch = 0; ch < 25; ++ch) {
      const int n = ch * 64 + lane;
      const bool p = (n < SLAB) && (ibest[n] == (unsigned char)wid);
      const unsigned long long m = __ballot(p);
      if (p) {
        const int pos = off + (int)__popcll(m & ((1ull << lane) - 1ull));
        nlist[pos] = (unsigned short)n;
      }
      off += (int)__popcll(m);
    }
  }
  __syncthreads();

  // phase 4: exports — ch0: s, ch1: g, ch2: packed lists + starts + dn
  for (int i = tid; i < SLAB; i += 512) {
    qp[i] = sbest[i];
    reinterpret_cast<unsigned int*>(qp + SP)[i] = (unsigned int)ibest[i];
  }
  unsigned int* ch2 = reinterpret_cast<unsigned int*>(qp + 2 * (size_t)SP);
  for (int i = tid; i < 784; i += 512)
    ch2[i] = (unsigned int)nlist[2*i] | ((unsigned int)nlist[2*i+1] << 16);
  if (tid < 9) ch2[784 + tid] = (unsigned int)starts[tid];
  if (tid < 8) reinterpret_cast<float*>(ch2)[800 + tid] = dnl[tid];
}

// ---------------- Kernel 3: y_{e,g}[c] = (seg-sum s*x + mean-pooled x)/(dn+1) ----------------
// grid: (b,f1,chalf) = 256 blocks, 320 threads = 40 groups x 8 lanes.
__global__ __launch_bounds__(320) void seg_k(
    float* qbuf, const float* __restrict__ x)
{
  const int bid = blockIdx.x;
  const int b   = bid >> 2;
  const int f1  = (bid >> 1) & 1;
  const int c0  = (bid & 1) * 64;

  __shared__ float        s_all[4][SLAB];    // 25088 B
  __shared__ unsigned int nl32[4][784];      // 12544 B
  __shared__ int          st_l[4][9];
  __shared__ float        inv_l[4][8];
  __shared__ float        yl[40][64];        // 10240 B

  const int tid = threadIdx.x;

  for (int e = 0; e < 4; ++e) {
    const float* qp = qbuf + (size_t)(b*4 + e) * 24 * SP + (size_t)(f1*28) * ROW;
    for (int i = tid; i < SLAB; i += 320) s_all[e][i] = qp[i];
    const unsigned int* ch2 = reinterpret_cast<const unsigned int*>(qp + 2 * (size_t)SP);
    for (int i = tid; i < 784; i += 320) nl32[e][i] = ch2[i];
    if (tid < 9) st_l[e][tid] = (int)ch2[784 + tid];
    if (tid < 8) inv_l[e][tid] = 1.f / (reinterpret_cast<const float*>(ch2)[800 + tid] + 1.f);
  }
  __syncthreads();

  const int grp = tid >> 3;   // 0..39
  const int l8  = tid & 7;
  const bool dyn = grp < 32;
  int e = 0, g = 0, i0 = 0, cnt = 0;
  if (dyn) { e = grp >> 3; g = grp & 7; i0 = st_l[e][g]; cnt = st_l[e][g+1] - i0; }
  else     { g = grp - 32; cnt = 196; }

  const float* xbase = x + (size_t)b * CIN * SP + (size_t)f1 * SLAB;
  for (int cl = 0; cl < 64; ++cl) {
    const float* xc = xbase + (size_t)(c0 + cl) * SP;
    float s = 0.f;
    if (dyn) {
      for (int i = l8; i < cnt; i += 8) {
        const int idx = i0 + i;
        const int n = (int)((nl32[e][idx >> 1] >> ((idx & 1) * 16)) & 0xFFFFu);
        s = fmaf(s_all[e][n], xc[n], s);
      }
    } else {
      const int nb = ((g >> 1) & 1) * 14 * 56 + (g >> 2) * 28 + (g & 1) * 14;
      for (int i = l8; i < 196; i += 8) {
        const int wl_ = i / 14, hl = i - wl_ * 14;
        s += xc[nb + wl_ * 56 + hl];
      }
    }
    s += __shfl_xor(s, 1); s += __shfl_xor(s, 2); s += __shfl_xor(s, 4);
    if (l8 == 0) yl[grp][cl] = s;
  }
  __syncthreads();

  float* yout = qbuf + ((size_t)b * 96 + 9 + f1 * 3) * SP;   // y[eg*128 + c]
  for (int k = tid; k < 32 * 64; k += 320) {
    const int eg = k >> 6, cl = k & 63;
    const int e2 = eg >> 3, g2 = eg & 7;
    yout[eg * 128 + c0 + cl] =
        (yl[eg][cl] + yl[32 + g2][cl] * (1.f / 196.f)) * inv_l[e2][g2];
  }
}

// ---------------- Kernel 4: proj[eg][co] = P_e y_eg + obp_e per (b,f1) ----------------
__global__ __launch_bounds__(256) void proj_k(
    float* qbuf, const float* __restrict__ P, const float* __restrict__ obp)
{
  const int bid = blockIdx.x;       // b*2 + f1
  const int b = bid >> 1, f1 = bid & 1;
  __shared__ float ylds[32][128];   // 16 KB
  const int tid = threadIdx.x;
  const float* yin = qbuf + ((size_t)b * 96 + 9 + f1 * 3) * SP;
  for (int i = tid; i < 32 * 128; i += 256) ylds[i >> 7][i & 127] = yin[i];
  __syncthreads();

  const int co = tid & 127;
  const int e0 = (tid >> 7) * 2;    // 0 or 2
  float a0[8], a1[8];
  const float o0 = obp[e0 * 128 + co], o1 = obp[(e0 + 1) * 128 + co];
  #pragma unroll
  for (int g = 0; g < 8; ++g) { a0[g] = o0; a1[g] = o1; }
  for (int ci = 0; ci < 128; ++ci) {
    const float p0 = P[((size_t)e0 * 128 + ci) * 128 + co];
    const float p1 = P[((size_t)(e0 + 1) * 128 + ci) * 128 + co];
    #pragma unroll
    for (int g = 0; g < 8; ++g) {
      a0[g] = fmaf(p0, ylds[e0 * 8 + g][ci], a0[g]);
      a1[g] = fmaf(p1, ylds[(e0 + 1) * 8 + g][ci], a1[g]);
    }
  }
  float* pout = qbuf + ((size_t)b * 96 + 3 + f1 * 3) * SP;
  #pragma unroll
  for (int g = 0; g < 8; ++g) {
    pout[(e0 * 8 + g) * 128 + co]       = a0[g];
    pout[((e0 + 1) * 8 + g) * 128 + co] = a1[g];
  }
}

// ---------------- Kernel 5: output via proj lookup; per (b,f1,rowpair) ----------------
__global__ __launch_bounds__(256) void out_k(
    const float* __restrict__ qbuf, const float* __restrict__ bo,
    float* __restrict__ out)
{
  const int bid = blockIdx.x;           // (b*2+f1)*14 + rp
  const int b   = bid / 28;
  const int rem = bid % 28;
  const int f1  = rem / 14;
  const int rp  = rem % 14;
  const int n0  = rp * 112;

  __shared__ float  proj_l[4096];
  __shared__ float4 s_l4[112];
  __shared__ unsigned int g_l[112];
  __shared__ float  out_l[56 * 132];

  const int tid = threadIdx.x;

  {
    const float4* pg = reinterpret_cast<const float4*>(
        qbuf + ((size_t)b * 96 + 3 + f1*3) * SP);
    float4* pl = reinterpret_cast<float4*>(proj_l);
    #pragma unroll
    for (int r = 0; r < 4; ++r) pl[tid + r * 256] = pg[tid + r * 256];
  }
  for (int i = tid; i < 112; i += 256) {
    float4 sv; unsigned int gp = 0;
    #pragma unroll
    for (int e = 0; e < 4; ++e) {
      const float* sp = qbuf + ((size_t)(b*4 + e) * 24) * SP + (size_t)(f1*28) * ROW;
      const float sval = sp[n0 + i];
      const unsigned int gv = reinterpret_cast<const unsigned int*>(sp + SP)[n0 + i];
      if (e == 0) sv.x = sval; else if (e == 1) sv.y = sval;
      else if (e == 2) sv.z = sval; else sv.w = sval;
      gp |= (gv & 7u) << (8 * e);
    }
    s_l4[i] = sv; g_l[i] = gp;
  }
  __syncthreads();

  const int cq  = tid & 31;
  const int sub = tid >> 5;
  const float4 bo4 = *reinterpret_cast<const float4*>(bo + cq * 4);
  const float4* pl4 = reinterpret_cast<const float4*>(proj_l);

  for (int chunk = 0; chunk < 2; ++chunk) {
    const int pbase = chunk * 56;
    #pragma unroll
    for (int i = 0; i < 7; ++i) {
      const int pxl = sub * 7 + i;
      const int px  = pbase + pxl;
      const float4 sv = s_l4[px];
      const unsigned int gp = g_l[px];
      float4 acc = bo4;
      {
        const float4 p = pl4[(0*8 + (gp        & 7u)) * 32 + cq];
        acc.x = fmaf(sv.x, p.x, acc.x); acc.y = fmaf(sv.x, p.y, acc.y);
        acc.z = fmaf(sv.x, p.z, acc.z); acc.w = fmaf(sv.x, p.w, acc.w);
      }
      {
        const float4 p = pl4[(1*8 + ((gp >> 8) & 7u)) * 32 + cq];
        acc.x = fmaf(sv.y, p.x, acc.x); acc.y = fmaf(sv.y, p.y, acc.y);
        acc.z = fmaf(sv.y, p.z, acc.z); acc.w = fmaf(sv.y, p.w, acc.w);
      }
      {
        const float4 p = pl4[(2*8 + ((gp >> 16) & 7u)) * 32 + cq];
        acc.x = fmaf(sv.z, p.x, acc.x); acc.y = fmaf(sv.z, p.y, acc.y);
        acc.z = fmaf(sv.z, p.z, acc.z); acc.w = fmaf(sv.z, p.w, acc.w);
      }
      {
        const float4 p = pl4[(3*8 + ((gp >> 24) & 7u)) * 32 + cq];
        acc.x = fmaf(sv.w, p.x, acc.x); acc.y = fmaf(sv.w, p.y, acc.y);
        acc.z = fmaf(sv.w, p.z, acc.z); acc.w = fmaf(sv.w, p.w, acc.w);
      }
      *reinterpret_cast<float4*>(&out_l[pxl * 132 + cq * 4]) = acc;
    }
    __syncthreads();
    for (int t = tid; t < 128 * 56; t += 256) {
      const int co = t / 56, pxl = t - co * 56;
      out[((size_t)b * 128 + co) * SP + (size_t)f1 * SLAB + n0 + pbase + pxl] =
          out_l[pxl * 132 + co];
    }
    __syncthreads();
  }
}

extern "C" void kernel_launch(void* const* d_in, const int* in_sizes, int n_in,
                              void* d_out, int out_size, void* d_ws, size_t ws_size,
                              hipStream_t stream) {
  const float* x  = (const float*)d_in[0];
  const float* Wc = (const float*)d_in[1];
  const float* bc = (const float*)d_in[2];
  const float* Wp = (const float*)d_in[3];
  const float* bp = (const float*)d_in[4];
  const float* sa = (const float*)d_in[5];
  const float* sb = (const float*)d_in[6];
  const float* Wo = (const float*)d_in[7];
  const float* bo = (const float*)d_in[8];
  float* out  = (float*)d_out;
  float* qbuf = (float*)d_ws;        // 77.1 MB; exports/y/proj reuse dead q channels
  float* Pbuf = out;                 // P (65536 f) + obp (512 f) in d_out scratch;
  float* obpb = out + 65536;         // read by proj_k, overwritten later by out_k

  pe_k   <<<dim3(4),       dim3(256), 0, stream>>>(Wo, Wp, bp, Pbuf, obpb);
  q_conv <<<dim3(64 * 49), dim3(128), 0, stream>>>(x, Wc, bc, qbuf);
  cluster_k<<<dim3(512),   dim3(512), 0, stream>>>(qbuf, sa, sb);
  seg_k  <<<dim3(256),     dim3(320), 0, stream>>>(qbuf, x);
  proj_k <<<dim3(128),     dim3(256), 0, stream>>>(qbuf, Pbuf, obpb);
  out_k  <<<dim3(1792),    dim3(256), 0, stream>>>(qbuf, bo, out);
}

// Round 11
// 323.360 us; speedup vs baseline: 2.0482x; 2.0482x over previous
//
#include <hip/hip_runtime.h>
#include <math.h>

#define CIN 128
#define HD  96
#define SP  3136   // 56*56
#define ROW 56
#define SLAB 1568  // 28*56

// ---------------- Kernel A: P[e][ci][co] = sum_c Wo[co][e*24+c]*Wp[e*24+c][ci]; obp ----------------
__global__ __launch_bounds__(256) void pe_k(
    const float* __restrict__ Wo, const float* __restrict__ Wp,
    const float* __restrict__ bp, float* __restrict__ P, float* __restrict__ obp)
{
  const int e = blockIdx.x;
  __shared__ float ws[24][128];
  const int tid = threadIdx.x;
  for (int i = tid; i < 24 * 128; i += 256)
    ws[i >> 7][i & 127] = Wp[(size_t)(e * 24 + (i >> 7)) * CIN + (i & 127)];
  __syncthreads();
  const int co = tid & 127;
  const int cig = tid >> 7;
  float wo_r[24];
  #pragma unroll
  for (int c = 0; c < 24; ++c) wo_r[c] = Wo[(size_t)co * HD + e * 24 + c];
  for (int ci = cig * 64; ci < cig * 64 + 64; ++ci) {
    float s = 0.f;
    #pragma unroll
    for (int c = 0; c < 24; ++c) s = fmaf(wo_r[c], ws[c][ci], s);
    P[((size_t)e * 128 + ci) * 128 + co] = s;
  }
  if (cig == 0) {
    float s = 0.f;
    #pragma unroll
    for (int c = 0; c < 24; ++c) s = fmaf(wo_r[c], bp[e * 24 + c], s);
    obp[e * 128 + co] = s;
  }
}

// ---------------- Kernel 1: q-only 1x1 conv (R4 structure, 96 outputs, 128 threads) ----------------
__global__ __launch_bounds__(128) void q_conv(
    const float* __restrict__ x, const float* __restrict__ Wc,
    const float* __restrict__ bc, float* __restrict__ qbuf)
{
  const int st = blockIdx.x % 49;
  const int b  = blockIdx.x / 49;
  const float* xb = x + (size_t)b * CIN * SP + st * 64;

  __shared__ float xs[32][64];      // 8 KB
  __shared__ float wl[32][100];     // 12.5 KB

  const int tid = threadIdx.x;
  const int og = tid >> 4;          // 0..7 -> o0 = og*12
  const int sg = tid & 15;          // 0..15 -> s0 = sg*4

  float acc[12][4];
  #pragma unroll
  for (int i = 0; i < 12; ++i) { acc[i][0]=0.f; acc[i][1]=0.f; acc[i][2]=0.f; acc[i][3]=0.f; }

  for (int kt = 0; kt < 4; ++kt) {
    __syncthreads();
    #pragma unroll
    for (int r = 0; r < 4; ++r) {
      int i = tid + r * 128;
      int cc = i >> 4, s4 = i & 15;
      float4 v = *reinterpret_cast<const float4*>(xb + (size_t)(kt*32 + cc) * SP + s4*4);
      *reinterpret_cast<float4*>(&xs[cc][s4*4]) = v;
    }
    #pragma unroll
    for (int r = 0; r < 6; ++r) {
      int i = tid + r * 128;        // 0..767: 96 rows x 8 float4
      int o  = i >> 3, c4 = i & 7;
      float4 wv = *reinterpret_cast<const float4*>(Wc + (size_t)o * CIN + kt*32 + c4*4);
      wl[c4*4+0][o] = wv.x; wl[c4*4+1][o] = wv.y;
      wl[c4*4+2][o] = wv.z; wl[c4*4+3][o] = wv.w;
    }
    __syncthreads();
    #pragma unroll
    for (int cc = 0; cc < 32; ++cc) {
      float xv[4];
      *reinterpret_cast<float4*>(xv) = *reinterpret_cast<const float4*>(&xs[cc][sg*4]);
      float wv[12];
      *reinterpret_cast<float4*>(wv + 0) = *reinterpret_cast<const float4*>(&wl[cc][og*12 + 0]);
      *reinterpret_cast<float4*>(wv + 4) = *reinterpret_cast<const float4*>(&wl[cc][og*12 + 4]);
      *reinterpret_cast<float4*>(wv + 8) = *reinterpret_cast<const float4*>(&wl[cc][og*12 + 8]);
      #pragma unroll
      for (int i = 0; i < 12; ++i)
        #pragma unroll
        for (int j = 0; j < 4; ++j)
          acc[i][j] = fmaf(wv[i], xv[j], acc[i][j]);
    }
  }
  #pragma unroll
  for (int i = 0; i < 12; ++i) {
    const int o = og * 12 + i;
    const float bias = bc[o];
    float4 v;
    v.x = acc[i][0] + bias; v.y = acc[i][1] + bias;
    v.z = acc[i][2] + bias; v.w = acc[i][3] + bias;
    *reinterpret_cast<float4*>(qbuf + ((size_t)b*96 + o) * SP + st*64 + sg*4) = v;
  }
}

// ---------------- Kernel 2: clustering per (b,e,f1); exports s (ch0), g (ch1), dn (ch2) ----------------
__global__ __launch_bounds__(512, 4) void cluster_k(
    float* qbuf, const float* __restrict__ alpha_p, const float* __restrict__ beta_p)
{
  const int blk = blockIdx.x;              // (b*4+e)*2 + f1
  const int f1  = blk & 1;
  const int be  = blk >> 1;
  const size_t base = (size_t)be * 24 * SP + (size_t)(f1 * 28) * ROW;
  float* qp = qbuf + base;

  __shared__ double cnd[24][8];
  __shared__ float  sbest[SLAB];
  __shared__ unsigned char ibest[SLAB];    // g = f2*4 + argmax (0..7)
  __shared__ float dnl[8];

  const int tid  = threadIdx.x;
  const int wid  = tid >> 6;
  const int lane = tid & 63;

  // phase 1: pooled q centers (wave per channel, 8 masked bins)
  for (int c = wid; c < 24; c += 8) {
    const float* src = qp + (size_t)c * SP;
    double b0=0,b1=0,b2=0,b3=0,b4=0,b5=0,b6=0,b7=0;
    for (int n = lane; n < SLAB; n += 64) {
      const int w = n / 56, h = n - w * 56;
      const int hf = (h >= 28) ? (h - 28) : h;
      const int g  = ((h >= 28) ? 4 : 0) + ((w >= 14) ? 2 : 0) + ((hf >= 14) ? 1 : 0);
      const double val = (double)src[n];
      b0 += (g==0)?val:0.0; b1 += (g==1)?val:0.0;
      b2 += (g==2)?val:0.0; b3 += (g==3)?val:0.0;
      b4 += (g==4)?val:0.0; b5 += (g==5)?val:0.0;
      b6 += (g==6)?val:0.0; b7 += (g==7)?val:0.0;
    }
    #pragma unroll
    for (int m = 32; m >= 1; m >>= 1) {
      b0 += __shfl_xor(b0,m); b1 += __shfl_xor(b1,m);
      b2 += __shfl_xor(b2,m); b3 += __shfl_xor(b3,m);
      b4 += __shfl_xor(b4,m); b5 += __shfl_xor(b5,m);
      b6 += __shfl_xor(b6,m); b7 += __shfl_xor(b7,m);
    }
    if (lane == 0) {
      cnd[c][0]=b0*(1.0/196.0); cnd[c][1]=b1*(1.0/196.0);
      cnd[c][2]=b2*(1.0/196.0); cnd[c][3]=b3*(1.0/196.0);
      cnd[c][4]=b4*(1.0/196.0); cnd[c][5]=b5*(1.0/196.0);
      cnd[c][6]=b6*(1.0/196.0); cnd[c][7]=b7*(1.0/196.0);
    }
  }
  __syncthreads();
  if (tid < 8) {
    double s = 0.0;
    #pragma unroll
    for (int c = 0; c < 24; ++c) { double t = cnd[c][tid]; s += t * t; }
    const double inv = 1.0 / fmax(sqrt(s), 1e-12);
    #pragma unroll
    for (int c = 0; c < 24; ++c) cnd[c][tid] *= inv;
  }
  __syncthreads();

  const double alpha = (double)alpha_p[0];
  const double beta  = (double)beta_p[0];

  // phase 2: fp64 z dots, strict-first argmax, one sigmoid
  for (int n0 = tid; n0 < SLAB; n0 += 512) {
    const int h  = n0 % 56;
    const int gb = (h >= 28) ? 4 : 0;
    double z0=0,z1=0,z2=0,z3=0,nrm=0;
    for (int c = 0; c < 24; ++c) {
      const double qv = (double)qp[(size_t)c * SP + n0];
      z0 += cnd[c][gb+0]*qv; z1 += cnd[c][gb+1]*qv;
      z2 += cnd[c][gb+2]*qv; z3 += cnd[c][gb+3]*qv;
      nrm += qv*qv;
    }
    const double inv = 1.0 / fmax(sqrt(nrm), 1e-12);
    const double v0 = beta + alpha * (z0 * inv);
    const double v1 = beta + alpha * (z1 * inv);
    const double v2 = beta + alpha * (z2 * inv);
    const double v3 = beta + alpha * (z3 * inv);
    double zb = v0; int bi = 0;
    if (v1 > zb) { zb = v1; bi = 1; }
    if (v2 > zb) { zb = v2; bi = 2; }
    if (v3 > zb) { zb = v3; bi = 3; }
    sbest[n0] = (float)(1.0 / (1.0 + exp(-zb)));
    ibest[n0] = (unsigned char)(gb + bi);
  }
  __syncthreads();

  // phase 3: dn per bin (wave k handles bin k)
  if (wid < 8) {
    float dn = 0.f;
    for (int ch = 0; ch < 25; ++ch) {
      const int n = ch * 64 + lane;
      const bool p = (n < SLAB) && (ibest[n] == (unsigned char)wid);
      dn += p ? sbest[n] : 0.f;
    }
    #pragma unroll
    for (int m = 32; m >= 1; m >>= 1) dn += __shfl_xor(dn, m);
    if (lane == 0) dnl[wid] = dn;
  }
  __syncthreads();

  // phase 4: exports — ch0: s, ch1: g (u32), ch2: dn[8]
  for (int i = tid; i < SLAB; i += 512) {
    qp[i] = sbest[i];
    reinterpret_cast<unsigned int*>(qp + SP)[i] = (unsigned int)ibest[i];
  }
  if (tid < 8) qp[2 * (size_t)SP + tid] = dnl[tid];
}

// ---------------- Kernel 3: y_{e,g}[c] = (masked segsum s*x + pooled x/196)/(dn+1) ----------------
// grid: (b,f1,cquarter) = 512 blocks, 512 threads; wave = channel (4 ch/wave), lanes = pixels.
__global__ __launch_bounds__(512, 4) void seg_k(
    float* qbuf, const float* __restrict__ x)
{
  const int bid = blockIdx.x;
  const int b   = bid >> 3;
  const int f1  = (bid >> 2) & 1;
  const int c0  = (bid & 3) * 32;

  __shared__ float s_l[4][SLAB];           // 25088 B
  __shared__ unsigned short gp_l[SLAB];    // 3136 B
  __shared__ float inv_l[4][8];

  const int tid = threadIdx.x;

  // stage s per head (coalesced)
  for (int e = 0; e < 4; ++e) {
    const float* qp = qbuf + (size_t)(b*4 + e) * 24 * SP + (size_t)(f1*28) * ROW;
    for (int i = tid; i < SLAB; i += 512) s_l[e][i] = qp[i];
  }
  // pack g from 4 heads: 3 bits each
  {
    const size_t hstride = (size_t)24 * SP;
    const unsigned int* g0 = reinterpret_cast<const unsigned int*>(
        qbuf + ((size_t)(b*4 + 0) * 24 + 1) * SP + (size_t)(f1*28) * ROW);
    const unsigned int* g1 = reinterpret_cast<const unsigned int*>(
        reinterpret_cast<const float*>(g0) + hstride);
    const unsigned int* g2 = reinterpret_cast<const unsigned int*>(
        reinterpret_cast<const float*>(g0) + 2 * hstride);
    const unsigned int* g3 = reinterpret_cast<const unsigned int*>(
        reinterpret_cast<const float*>(g0) + 3 * hstride);
    for (int i = tid; i < SLAB; i += 512)
      gp_l[i] = (unsigned short)((g0[i] & 7u) | ((g1[i] & 7u) << 3) |
                                 ((g2[i] & 7u) << 6) | ((g3[i] & 7u) << 9));
  }
  if (tid < 32) {
    const int e = tid >> 3, g = tid & 7;
    const float* dnp = qbuf + ((size_t)(b*4 + e) * 24 + 2) * SP + (size_t)(f1*28) * ROW;
    inv_l[e][g] = 1.f / (dnp[g] + 1.f);
  }
  __syncthreads();

  const int wid  = tid >> 6;
  const int lane = tid & 63;
  const float* xbase = x + (size_t)b * CIN * SP + (size_t)f1 * SLAB;

  for (int ci = 0; ci < 4; ++ci) {
    const int c = c0 + wid * 4 + ci;
    const float* xc = xbase + (size_t)c * SP;
    float sa[32], xp[8];
    #pragma unroll
    for (int i = 0; i < 32; ++i) sa[i] = 0.f;
    #pragma unroll
    for (int i = 0; i < 8; ++i) xp[i] = 0.f;

    for (int n = lane; n < SLAB; n += 64) {
      const float xv = xc[n];
      const unsigned int gp = (unsigned int)gp_l[n];
      const int q56 = (n * 18725) >> 20;                 // n/56 (exact for n<43690)
      const int h   = n - q56 * 56;
      const int hf  = (h >= 28) ? (h - 28) : h;
      const int gm  = ((h >= 28) ? 4 : 0) + ((q56 >= 14) ? 2 : 0) + ((hf >= 14) ? 1 : 0);
      #pragma unroll
      for (int k = 0; k < 8; ++k) xp[k] += (gm == k) ? xv : 0.f;
      const float w0 = s_l[0][n] * xv;
      const float w1 = s_l[1][n] * xv;
      const float w2 = s_l[2][n] * xv;
      const float w3 = s_l[3][n] * xv;
      const int g0 = gp & 7, g1 = (gp >> 3) & 7, g2 = (gp >> 6) & 7, g3 = (gp >> 9) & 7;
      #pragma unroll
      for (int k = 0; k < 8; ++k) {
        sa[k]      += (g0 == k) ? w0 : 0.f;
        sa[8 + k]  += (g1 == k) ? w1 : 0.f;
        sa[16 + k] += (g2 == k) ? w2 : 0.f;
        sa[24 + k] += (g3 == k) ? w3 : 0.f;
      }
    }
    #pragma unroll
    for (int m = 32; m >= 1; m >>= 1) {
      #pragma unroll
      for (int i = 0; i < 32; ++i) sa[i] += __shfl_xor(sa[i], m);
      #pragma unroll
      for (int i = 0; i < 8; ++i) xp[i] += __shfl_xor(xp[i], m);
    }
    if (lane == 0) {
      float* yout = qbuf + ((size_t)b * 96 + 9 + f1 * 3) * SP;   // y[eg*128 + c]
      #pragma unroll
      for (int eg = 0; eg < 32; ++eg)
        yout[eg * 128 + c] =
            (sa[eg] + xp[eg & 7] * (1.f / 196.f)) * inv_l[eg >> 3][eg & 7];
    }
  }
}

// ---------------- Kernel 4: proj[eg][co] = P_e y_eg + obp_e per (b,f1) ----------------
__global__ __launch_bounds__(256) void proj_k(
    float* qbuf, const float* __restrict__ P, const float* __restrict__ obp)
{
  const int bid = blockIdx.x;       // b*2 + f1
  const int b = bid >> 1, f1 = bid & 1;
  __shared__ float ylds[32][128];   // 16 KB
  const int tid = threadIdx.x;
  const float* yin = qbuf + ((size_t)b * 96 + 9 + f1 * 3) * SP;
  for (int i = tid; i < 32 * 128; i += 256) ylds[i >> 7][i & 127] = yin[i];
  __syncthreads();

  const int co = tid & 127;
  const int e0 = (tid >> 7) * 2;    // 0 or 2
  float a0[8], a1[8];
  const float o0 = obp[e0 * 128 + co], o1 = obp[(e0 + 1) * 128 + co];
  #pragma unroll
  for (int g = 0; g < 8; ++g) { a0[g] = o0; a1[g] = o1; }
  for (int ci = 0; ci < 128; ++ci) {
    const float p0 = P[((size_t)e0 * 128 + ci) * 128 + co];
    const float p1 = P[((size_t)(e0 + 1) * 128 + ci) * 128 + co];
    #pragma unroll
    for (int g = 0; g < 8; ++g) {
      a0[g] = fmaf(p0, ylds[e0 * 8 + g][ci], a0[g]);
      a1[g] = fmaf(p1, ylds[(e0 + 1) * 8 + g][ci], a1[g]);
    }
  }
  float* pout = qbuf + ((size_t)b * 96 + 3 + f1 * 3) * SP;
  #pragma unroll
  for (int g = 0; g < 8; ++g) {
    pout[(e0 * 8 + g) * 128 + co]       = a0[g];
    pout[((e0 + 1) * 8 + g) * 128 + co] = a1[g];
  }
}

// ---------------- Kernel 5: output via proj lookup; per (b,f1,rowpair) ----------------
__global__ __launch_bounds__(256) void out_k(
    const float* __restrict__ qbuf, const float* __restrict__ bo,
    float* __restrict__ out)
{
  const int bid = blockIdx.x;           // (b*2+f1)*14 + rp
  const int b   = bid / 28;
  const int rem = bid % 28;
  const int f1  = rem / 14;
  const int rp  = rem % 14;
  const int n0  = rp * 112;

  __shared__ float  proj_l[4096];
  __shared__ float4 s_l4[112];
  __shared__ unsigned int g_l[112];
  __shared__ float  out_l[56 * 132];

  const int tid = threadIdx.x;

  {
    const float4* pg = reinterpret_cast<const float4*>(
        qbuf + ((size_t)b * 96 + 3 + f1*3) * SP);
    float4* pl = reinterpret_cast<float4*>(proj_l);
    #pragma unroll
    for (int r = 0; r < 4; ++r) pl[tid + r * 256] = pg[tid + r * 256];
  }
  for (int i = tid; i < 112; i += 256) {
    float4 sv; unsigned int gp = 0;
    #pragma unroll
    for (int e = 0; e < 4; ++e) {
      const float* sp = qbuf + ((size_t)(b*4 + e) * 24) * SP + (size_t)(f1*28) * ROW;
      const float sval = sp[n0 + i];
      const unsigned int gv = reinterpret_cast<const unsigned int*>(sp + SP)[n0 + i];
      if (e == 0) sv.x = sval; else if (e == 1) sv.y = sval;
      else if (e == 2) sv.z = sval; else sv.w = sval;
      gp |= (gv & 7u) << (8 * e);
    }
    s_l4[i] = sv; g_l[i] = gp;
  }
  __syncthreads();

  const int cq  = tid & 31;
  const int sub = tid >> 5;
  const float4 bo4 = *reinterpret_cast<const float4*>(bo + cq * 4);
  const float4* pl4 = reinterpret_cast<const float4*>(proj_l);

  for (int chunk = 0; chunk < 2; ++chunk) {
    const int pbase = chunk * 56;
    #pragma unroll
    for (int i = 0; i < 7; ++i) {
      const int pxl = sub * 7 + i;
      const int px  = pbase + pxl;
      const float4 sv = s_l4[px];
      const unsigned int gp = g_l[px];
      float4 acc = bo4;
      {
        const float4 p = pl4[(0*8 + (gp        & 7u)) * 32 + cq];
        acc.x = fmaf(sv.x, p.x, acc.x); acc.y = fmaf(sv.x, p.y, acc.y);
        acc.z = fmaf(sv.x, p.z, acc.z); acc.w = fmaf(sv.x, p.w, acc.w);
      }
      {
        const float4 p = pl4[(1*8 + ((gp >> 8) & 7u)) * 32 + cq];
        acc.x = fmaf(sv.y, p.x, acc.x); acc.y = fmaf(sv.y, p.y, acc.y);
        acc.z = fmaf(sv.y, p.z, acc.z); acc.w = fmaf(sv.y, p.w, acc.w);
      }
      {
        const float4 p = pl4[(2*8 + ((gp >> 16) & 7u)) * 32 + cq];
        acc.x = fmaf(sv.z, p.x, acc.x); acc.y = fmaf(sv.z, p.y, acc.y);
        acc.z = fmaf(sv.z, p.z, acc.z); acc.w = fmaf(sv.z, p.w, acc.w);
      }
      {
        const float4 p = pl4[(3*8 + ((gp >> 24) & 7u)) * 32 + cq];
        acc.x = fmaf(sv.w, p.x, acc.x); acc.y = fmaf(sv.w, p.y, acc.y);
        acc.z = fmaf(sv.w, p.z, acc.z); acc.w = fmaf(sv.w, p.w, acc.w);
      }
      *reinterpret_cast<float4*>(&out_l[pxl * 132 + cq * 4]) = acc;
    }
    __syncthreads();
    for (int t = tid; t < 128 * 56; t += 256) {
      const int co = t / 56, pxl = t - co * 56;
      out[((size_t)b * 128 + co) * SP + (size_t)f1 * SLAB + n0 + pbase + pxl] =
          out_l[pxl * 132 + co];
    }
    __syncthreads();
  }
}

extern "C" void kernel_launch(void* const* d_in, const int* in_sizes, int n_in,
                              void* d_out, int out_size, void* d_ws, size_t ws_size,
                              hipStream_t stream) {
  const float* x  = (const float*)d_in[0];
  const float* Wc = (const float*)d_in[1];
  const float* bc = (const float*)d_in[2];
  const float* Wp = (const float*)d_in[3];
  const float* bp = (const float*)d_in[4];
  const float* sa = (const float*)d_in[5];
  const float* sb = (const float*)d_in[6];
  const float* Wo = (const float*)d_in[7];
  const float* bo = (const float*)d_in[8];
  float* out  = (float*)d_out;
  float* qbuf = (float*)d_ws;        // 77.1 MB; exports/y/proj reuse dead q channels
  float* Pbuf = out;                 // P (65536 f) + obp (512 f) in d_out scratch;
  float* obpb = out + 65536;         // consumed by proj_k before out_k overwrites

  pe_k     <<<dim3(4),       dim3(256), 0, stream>>>(Wo, Wp, bp, Pbuf, obpb);
  q_conv   <<<dim3(64 * 49), dim3(128), 0, stream>>>(x, Wc, bc, qbuf);
  cluster_k<<<dim3(512),     dim3(512), 0, stream>>>(qbuf, sa, sb);
  seg_k    <<<dim3(512),     dim3(512), 0, stream>>>(qbuf, x);
  proj_k   <<<dim3(128),     dim3(256), 0, stream>>>(qbuf, Pbuf, obpb);
  out_k    <<<dim3(1792),    dim3(256), 0, stream>>>(qbuf, bo, out);
}

// Round 12
// 230.051 us; speedup vs baseline: 2.8790x; 1.4056x over previous
//
#include <hip/hip_runtime.h>
#include <math.h>

#define CIN 128
#define HD  96
#define SP  3136   // 56*56
#define ROW 56
#define SLAB 1568  // 28*56
#define YSTRIDE 9216   // per-(b,f1) y-partial block: 64*128 + 8*128

// ---------------- Kernel A: P[e][ci][co] = sum_c Wo[co][e*24+c]*Wp[e*24+c][ci]; obp ----------------
__global__ __launch_bounds__(256) void pe_k(
    const float* __restrict__ Wo, const float* __restrict__ Wp,
    const float* __restrict__ bp, float* __restrict__ P, float* __restrict__ obp)
{
  const int e = blockIdx.x;
  __shared__ float ws[24][128];
  const int tid = threadIdx.x;
  for (int i = tid; i < 24 * 128; i += 256)
    ws[i >> 7][i & 127] = Wp[(size_t)(e * 24 + (i >> 7)) * CIN + (i & 127)];
  __syncthreads();
  const int co = tid & 127;
  const int cig = tid >> 7;
  float wo_r[24];
  #pragma unroll
  for (int c = 0; c < 24; ++c) wo_r[c] = Wo[(size_t)co * HD + e * 24 + c];
  for (int ci = cig * 64; ci < cig * 64 + 64; ++ci) {
    float s = 0.f;
    #pragma unroll
    for (int c = 0; c < 24; ++c) s = fmaf(wo_r[c], ws[c][ci], s);
    P[((size_t)e * 128 + ci) * 128 + co] = s;
  }
  if (cig == 0) {
    float s = 0.f;
    #pragma unroll
    for (int c = 0; c < 24; ++c) s = fmaf(wo_r[c], bp[e * 24 + c], s);
    obp[e * 128 + co] = s;
  }
}

// ---------------- Kernel 1: q-only 1x1 conv (unchanged) ----------------
__global__ __launch_bounds__(128) void q_conv(
    const float* __restrict__ x, const float* __restrict__ Wc,
    const float* __restrict__ bc, float* __restrict__ qbuf)
{
  const int st = blockIdx.x % 49;
  const int b  = blockIdx.x / 49;
  const float* xb = x + (size_t)b * CIN * SP + st * 64;

  __shared__ float xs[32][64];
  __shared__ float wl[32][100];

  const int tid = threadIdx.x;
  const int og = tid >> 4;
  const int sg = tid & 15;

  float acc[12][4];
  #pragma unroll
  for (int i = 0; i < 12; ++i) { acc[i][0]=0.f; acc[i][1]=0.f; acc[i][2]=0.f; acc[i][3]=0.f; }

  for (int kt = 0; kt < 4; ++kt) {
    __syncthreads();
    #pragma unroll
    for (int r = 0; r < 4; ++r) {
      int i = tid + r * 128;
      int cc = i >> 4, s4 = i & 15;
      float4 v = *reinterpret_cast<const float4*>(xb + (size_t)(kt*32 + cc) * SP + s4*4);
      *reinterpret_cast<float4*>(&xs[cc][s4*4]) = v;
    }
    #pragma unroll
    for (int r = 0; r < 6; ++r) {
      int i = tid + r * 128;
      int o  = i >> 3, c4 = i & 7;
      float4 wv = *reinterpret_cast<const float4*>(Wc + (size_t)o * CIN + kt*32 + c4*4);
      wl[c4*4+0][o] = wv.x; wl[c4*4+1][o] = wv.y;
      wl[c4*4+2][o] = wv.z; wl[c4*4+3][o] = wv.w;
    }
    __syncthreads();
    #pragma unroll
    for (int cc = 0; cc < 32; ++cc) {
      float xv[4];
      *reinterpret_cast<float4*>(xv) = *reinterpret_cast<const float4*>(&xs[cc][sg*4]);
      float wv[12];
      *reinterpret_cast<float4*>(wv + 0) = *reinterpret_cast<const float4*>(&wl[cc][og*12 + 0]);
      *reinterpret_cast<float4*>(wv + 4) = *reinterpret_cast<const float4*>(&wl[cc][og*12 + 4]);
      *reinterpret_cast<float4*>(wv + 8) = *reinterpret_cast<const float4*>(&wl[cc][og*12 + 8]);
      #pragma unroll
      for (int i = 0; i < 12; ++i)
        #pragma unroll
        for (int j = 0; j < 4; ++j)
          acc[i][j] = fmaf(wv[i], xv[j], acc[i][j]);
    }
  }
  #pragma unroll
  for (int i = 0; i < 12; ++i) {
    const int o = og * 12 + i;
    const float bias = bc[o];
    float4 v;
    v.x = acc[i][0] + bias; v.y = acc[i][1] + bias;
    v.z = acc[i][2] + bias; v.w = acc[i][3] + bias;
    *reinterpret_cast<float4*>(qbuf + ((size_t)b*96 + o) * SP + st*64 + sg*4) = v;
  }
}

// ---------------- Kernel 2: clustering per (b,e,f1); exports s (ch0), g (ch1), dn (ch2) ----------------
__global__ __launch_bounds__(512, 4) void cluster_k(
    float* qbuf, const float* __restrict__ alpha_p, const float* __restrict__ beta_p)
{
  const int blk = blockIdx.x;              // (b*4+e)*2 + f1
  const int f1  = blk & 1;
  const int be  = blk >> 1;
  const size_t base = (size_t)be * 24 * SP + (size_t)(f1 * 28) * ROW;
  float* qp = qbuf + base;

  __shared__ double cnd[24][8];
  __shared__ float  sbest[SLAB];
  __shared__ unsigned char ibest[SLAB];
  __shared__ float dnl[8];

  const int tid  = threadIdx.x;
  const int wid  = tid >> 6;
  const int lane = tid & 63;

  for (int c = wid; c < 24; c += 8) {
    const float* src = qp + (size_t)c * SP;
    double b0=0,b1=0,b2=0,b3=0,b4=0,b5=0,b6=0,b7=0;
    for (int n = lane; n < SLAB; n += 64) {
      const int w = n / 56, h = n - w * 56;
      const int hf = (h >= 28) ? (h - 28) : h;
      const int g  = ((h >= 28) ? 4 : 0) + ((w >= 14) ? 2 : 0) + ((hf >= 14) ? 1 : 0);
      const double val = (double)src[n];
      b0 += (g==0)?val:0.0; b1 += (g==1)?val:0.0;
      b2 += (g==2)?val:0.0; b3 += (g==3)?val:0.0;
      b4 += (g==4)?val:0.0; b5 += (g==5)?val:0.0;
      b6 += (g==6)?val:0.0; b7 += (g==7)?val:0.0;
    }
    #pragma unroll
    for (int m = 32; m >= 1; m >>= 1) {
      b0 += __shfl_xor(b0,m); b1 += __shfl_xor(b1,m);
      b2 += __shfl_xor(b2,m); b3 += __shfl_xor(b3,m);
      b4 += __shfl_xor(b4,m); b5 += __shfl_xor(b5,m);
      b6 += __shfl_xor(b6,m); b7 += __shfl_xor(b7,m);
    }
    if (lane == 0) {
      cnd[c][0]=b0*(1.0/196.0); cnd[c][1]=b1*(1.0/196.0);
      cnd[c][2]=b2*(1.0/196.0); cnd[c][3]=b3*(1.0/196.0);
      cnd[c][4]=b4*(1.0/196.0); cnd[c][5]=b5*(1.0/196.0);
      cnd[c][6]=b6*(1.0/196.0); cnd[c][7]=b7*(1.0/196.0);
    }
  }
  __syncthreads();
  if (tid < 8) {
    double s = 0.0;
    #pragma unroll
    for (int c = 0; c < 24; ++c) { double t = cnd[c][tid]; s += t * t; }
    const double inv = 1.0 / fmax(sqrt(s), 1e-12);
    #pragma unroll
    for (int c = 0; c < 24; ++c) cnd[c][tid] *= inv;
  }
  __syncthreads();

  const double alpha = (double)alpha_p[0];
  const double beta  = (double)beta_p[0];

  for (int n0 = tid; n0 < SLAB; n0 += 512) {
    const int h  = n0 % 56;
    const int gb = (h >= 28) ? 4 : 0;
    double z0=0,z1=0,z2=0,z3=0,nrm=0;
    for (int c = 0; c < 24; ++c) {
      const double qv = (double)qp[(size_t)c * SP + n0];
      z0 += cnd[c][gb+0]*qv; z1 += cnd[c][gb+1]*qv;
      z2 += cnd[c][gb+2]*qv; z3 += cnd[c][gb+3]*qv;
      nrm += qv*qv;
    }
    const double inv = 1.0 / fmax(sqrt(nrm), 1e-12);
    const double v0 = beta + alpha * (z0 * inv);
    const double v1 = beta + alpha * (z1 * inv);
    const double v2 = beta + alpha * (z2 * inv);
    const double v3 = beta + alpha * (z3 * inv);
    double zb = v0; int bi = 0;
    if (v1 > zb) { zb = v1; bi = 1; }
    if (v2 > zb) { zb = v2; bi = 2; }
    if (v3 > zb) { zb = v3; bi = 3; }
    sbest[n0] = (float)(1.0 / (1.0 + exp(-zb)));
    ibest[n0] = (unsigned char)(gb + bi);
  }
  __syncthreads();

  if (wid < 8) {
    float dn = 0.f;
    for (int ch = 0; ch < 25; ++ch) {
      const int n = ch * 64 + lane;
      const bool p = (n < SLAB) && (ibest[n] == (unsigned char)wid);
      dn += p ? sbest[n] : 0.f;
    }
    #pragma unroll
    for (int m = 32; m >= 1; m >>= 1) dn += __shfl_xor(dn, m);
    if (lane == 0) dnl[wid] = dn;
  }
  __syncthreads();

  for (int i = tid; i < SLAB; i += 512) {
    qp[i] = sbest[i];
    reinterpret_cast<unsigned int*>(qp + SP)[i] = (unsigned int)ibest[i];
  }
  if (tid < 8) qp[2 * (size_t)SP + tid] = dnl[tid];
}

// ---------------- Kernel 3: seg sums, transposed (lane=channel, pixel wave-uniform) ----------------
// Block = (b,f1,f2,wh): 392 px. sa[16] regs (4 heads x 4 bins), pool xp[2].
// Uniform-branch FMA dispatch via readfirstlane(g).
__global__ __launch_bounds__(256, 2) void seg_k(
    float* qbuf, const float* __restrict__ x)
{
  const int bid = blockIdx.x;            // ((b*2+f1)*2+f2)*2+wh
  const int wh  = bid & 1;
  const int f2  = (bid >> 1) & 1;
  const int f1  = (bid >> 2) & 1;
  const int b   = bid >> 3;

  __shared__ float4 sq_l[392];           // s of 4 heads per pixel
  __shared__ unsigned int gq_l[392];     // (g&3) packed 2b x 4 heads
  __shared__ float xT[56][130];          // transposed x chunk (2 rows x 28 cols)
  __shared__ float ysum[16][128];
  __shared__ float xps[2][128];

  const int tid = threadIdx.x;
  const int c   = tid & 127;
  const int pg  = tid >> 7;              // pixel parity group (wave-uniform)

  // stage s/g for this block's 392 pixels
  for (int n = tid; n < 392; n += 256) {
    const int r = n / 28, hc = n - r * 28;
    const int n_slab = (wh * 14 + r) * 56 + f2 * 28 + hc;
    float4 s4; unsigned int gp = 0;
    #pragma unroll
    for (int e = 0; e < 4; ++e) {
      const float* qp = qbuf + (size_t)(b*4 + e) * 24 * SP + (size_t)(f1*28) * ROW;
      const float sv = qp[n_slab];
      const unsigned int gv = reinterpret_cast<const unsigned int*>(qp + SP)[n_slab];
      if (e==0) s4.x = sv; else if (e==1) s4.y = sv;
      else if (e==2) s4.z = sv; else s4.w = sv;
      gp |= (gv & 3u) << (2*e);
    }
    sq_l[n] = s4; gq_l[n] = gp;
  }

  float sa[16];
  #pragma unroll
  for (int i = 0; i < 16; ++i) sa[i] = 0.f;
  float xp0 = 0.f, xp1 = 0.f;

  const float* xb = x + (size_t)b * CIN * SP;
  const int rowbase = f1*28 + wh*14;

  for (int ch = 0; ch < 7; ++ch) {
    __syncthreads();
    // stage xT: 2 rows x 28 cols x 128 ch = 1792 float4 tasks
    #pragma unroll
    for (int k = 0; k < 7; ++k) {
      const int slot = tid + k * 256;
      const int c2 = slot / 14, p4 = slot - c2 * 14;
      const int rr = p4 / 7, col4 = p4 - rr * 7;
      const int w = rowbase + ch*2 + rr;
      const float4 v = *reinterpret_cast<const float4*>(
          xb + (size_t)c2 * SP + (size_t)w * ROW + f2*28 + col4*4);
      const int pxl = rr * 28 + col4 * 4;
      xT[pxl+0][c2] = v.x; xT[pxl+1][c2] = v.y;
      xT[pxl+2][c2] = v.z; xT[pxl+3][c2] = v.w;
    }
    __syncthreads();
    // 28 pixels for this pg; n wave-uniform
    for (int i = 0; i < 28; ++i) {
      const int pxl = 2*i + pg;
      const int n   = ch*56 + pxl;
      const float4 s4 = sq_l[n];
      const int gp = __builtin_amdgcn_readfirstlane((int)gq_l[n]);
      const float xv = xT[pxl][c];
      {
        const int k = gp & 3;
        if      (k == 0) sa[0]  += s4.x * xv;
        else if (k == 1) sa[1]  += s4.x * xv;
        else if (k == 2) sa[2]  += s4.x * xv;
        else             sa[3]  += s4.x * xv;
      }
      {
        const int k = (gp >> 2) & 3;
        if      (k == 0) sa[4]  += s4.y * xv;
        else if (k == 1) sa[5]  += s4.y * xv;
        else if (k == 2) sa[6]  += s4.y * xv;
        else             sa[7]  += s4.y * xv;
      }
      {
        const int k = (gp >> 4) & 3;
        if      (k == 0) sa[8]  += s4.z * xv;
        else if (k == 1) sa[9]  += s4.z * xv;
        else if (k == 2) sa[10] += s4.z * xv;
        else             sa[11] += s4.z * xv;
      }
      {
        const int k = (gp >> 6) & 3;
        if      (k == 0) sa[12] += s4.w * xv;
        else if (k == 1) sa[13] += s4.w * xv;
        else if (k == 2) sa[14] += s4.w * xv;
        else             sa[15] += s4.w * xv;
      }
      const int hc = (pxl >= 28) ? (pxl - 28) : pxl;
      if (hc >= 14) xp1 += xv; else xp0 += xv;
    }
  }

  // reduce pg partials via LDS, then write y-partials + pool rows
  __syncthreads();
  if (pg == 0) {
    #pragma unroll
    for (int k = 0; k < 16; ++k) ysum[k][c] = sa[k];
    xps[0][c] = xp0; xps[1][c] = xp1;
  }
  __syncthreads();
  if (pg == 1) {
    #pragma unroll
    for (int k = 0; k < 16; ++k) ysum[k][c] += sa[k];
    xps[0][c] += xp0; xps[1][c] += xp1;
  }
  __syncthreads();

  float* ybase = qbuf + ((size_t)b*96 + 9) * SP + (size_t)f1 * YSTRIDE;
  for (int i = tid; i < 16*128; i += 256) {
    const int row = i >> 7, cc = i & 127;
    ybase[((wh*2 + f2)*16 + row)*128 + cc] = ysum[row][cc];
  }
  {
    const int hb = tid >> 7, cc = tid & 127;
    ybase[64*128 + (f2*4 + wh*2 + hb)*128 + cc] = xps[hb][cc];
  }
}

// ---------------- Kernel 4: proj[eg][co] = P_e y_eg + obp_e per (b,f1); combines y-partials ----------------
__global__ __launch_bounds__(256) void proj_k(
    float* qbuf, const float* __restrict__ P, const float* __restrict__ obp)
{
  const int bid = blockIdx.x;       // b*2 + f1
  const int b = bid >> 1, f1 = bid & 1;
  __shared__ float ylds[32][128];
  __shared__ float invs[32];
  const int tid = threadIdx.x;

  if (tid < 32) {
    const int e = tid >> 3, g = tid & 7;
    const float* dnp = qbuf + ((size_t)(b*4 + e) * 24 + 2) * SP + (size_t)(f1*28) * ROW;
    invs[tid] = 1.f / (dnp[g] + 1.f);
  }
  __syncthreads();

  const float* yp = qbuf + ((size_t)b*96 + 9) * SP + (size_t)f1 * YSTRIDE;
  for (int i = tid; i < 32*128; i += 256) {
    const int eg = i >> 7, cc = i & 127;
    const int e = eg >> 3, g = eg & 7, ff2 = g >> 2, m = g & 3;
    const float v = yp[((0 + ff2)*16 + e*4 + m)*128 + cc]
                  + yp[((2 + ff2)*16 + e*4 + m)*128 + cc]
                  + yp[64*128 + g*128 + cc] * (1.f/196.f);
    ylds[eg][cc] = v * invs[eg];
  }
  __syncthreads();

  const int co = tid & 127;
  const int e0 = (tid >> 7) * 2;
  float a0[8], a1[8];
  const float o0 = obp[e0 * 128 + co], o1 = obp[(e0 + 1) * 128 + co];
  #pragma unroll
  for (int g = 0; g < 8; ++g) { a0[g] = o0; a1[g] = o1; }
  for (int ci = 0; ci < 128; ++ci) {
    const float p0 = P[((size_t)e0 * 128 + ci) * 128 + co];
    const float p1 = P[((size_t)(e0 + 1) * 128 + ci) * 128 + co];
    #pragma unroll
    for (int g = 0; g < 8; ++g) {
      a0[g] = fmaf(p0, ylds[e0 * 8 + g][ci], a0[g]);
      a1[g] = fmaf(p1, ylds[(e0 + 1) * 8 + g][ci], a1[g]);
    }
  }
  float* pout = qbuf + ((size_t)b * 96 + 3 + f1 * 3) * SP;
  #pragma unroll
  for (int g = 0; g < 8; ++g) {
    pout[(e0 * 8 + g) * 128 + co]       = a0[g];
    pout[((e0 + 1) * 8 + g) * 128 + co] = a1[g];
  }
}

// ---------------- Kernel 5: output via proj lookup (unchanged) ----------------
__global__ __launch_bounds__(256) void out_k(
    const float* __restrict__ qbuf, const float* __restrict__ bo,
    float* __restrict__ out)
{
  const int bid = blockIdx.x;           // (b*2+f1)*14 + rp
  const int b   = bid / 28;
  const int rem = bid % 28;
  const int f1  = rem / 14;
  const int rp  = rem % 14;
  const int n0  = rp * 112;

  __shared__ float  proj_l[4096];
  __shared__ float4 s_l4[112];
  __shared__ unsigned int g_l[112];
  __shared__ float  out_l[56 * 132];

  const int tid = threadIdx.x;

  {
    const float4* pg = reinterpret_cast<const float4*>(
        qbuf + ((size_t)b * 96 + 3 + f1*3) * SP);
    float4* pl = reinterpret_cast<float4*>(proj_l);
    #pragma unroll
    for (int r = 0; r < 4; ++r) pl[tid + r * 256] = pg[tid + r * 256];
  }
  for (int i = tid; i < 112; i += 256) {
    float4 sv; unsigned int gp = 0;
    #pragma unroll
    for (int e = 0; e < 4; ++e) {
      const float* sp = qbuf + ((size_t)(b*4 + e) * 24) * SP + (size_t)(f1*28) * ROW;
      const float sval = sp[n0 + i];
      const unsigned int gv = reinterpret_cast<const unsigned int*>(sp + SP)[n0 + i];
      if (e == 0) sv.x = sval; else if (e == 1) sv.y = sval;
      else if (e == 2) sv.z = sval; else sv.w = sval;
      gp |= (gv & 7u) << (8 * e);
    }
    s_l4[i] = sv; g_l[i] = gp;
  }
  __syncthreads();

  const int cq  = tid & 31;
  const int sub = tid >> 5;
  const float4 bo4 = *reinterpret_cast<const float4*>(bo + cq * 4);
  const float4* pl4 = reinterpret_cast<const float4*>(proj_l);

  for (int chunk = 0; chunk < 2; ++chunk) {
    const int pbase = chunk * 56;
    #pragma unroll
    for (int i = 0; i < 7; ++i) {
      const int pxl = sub * 7 + i;
      const int px  = pbase + pxl;
      const float4 sv = s_l4[px];
      const unsigned int gp = g_l[px];
      float4 acc = bo4;
      {
        const float4 p = pl4[(0*8 + (gp        & 7u)) * 32 + cq];
        acc.x = fmaf(sv.x, p.x, acc.x); acc.y = fmaf(sv.x, p.y, acc.y);
        acc.z = fmaf(sv.x, p.z, acc.z); acc.w = fmaf(sv.x, p.w, acc.w);
      }
      {
        const float4 p = pl4[(1*8 + ((gp >> 8) & 7u)) * 32 + cq];
        acc.x = fmaf(sv.y, p.x, acc.x); acc.y = fmaf(sv.y, p.y, acc.y);
        acc.z = fmaf(sv.y, p.z, acc.z); acc.w = fmaf(sv.y, p.w, acc.w);
      }
      {
        const float4 p = pl4[(2*8 + ((gp >> 16) & 7u)) * 32 + cq];
        acc.x = fmaf(sv.z, p.x, acc.x); acc.y = fmaf(sv.z, p.y, acc.y);
        acc.z = fmaf(sv.z, p.z, acc.z); acc.w = fmaf(sv.z, p.w, acc.w);
      }
      {
        const float4 p = pl4[(3*8 + ((gp >> 24) & 7u)) * 32 + cq];
        acc.x = fmaf(sv.w, p.x, acc.x); acc.y = fmaf(sv.w, p.y, acc.y);
        acc.z = fmaf(sv.w, p.z, acc.z); acc.w = fmaf(sv.w, p.w, acc.w);
      }
      *reinterpret_cast<float4*>(&out_l[pxl * 132 + cq * 4]) = acc;
    }
    __syncthreads();
    for (int t = tid; t < 128 * 56; t += 256) {
      const int co = t / 56, pxl = t - co * 56;
      out[((size_t)b * 128 + co) * SP + (size_t)f1 * SLAB + n0 + pbase + pxl] =
          out_l[pxl * 132 + co];
    }
    __syncthreads();
  }
}

extern "C" void kernel_launch(void* const* d_in, const int* in_sizes, int n_in,
                              void* d_out, int out_size, void* d_ws, size_t ws_size,
                              hipStream_t stream) {
  const float* x  = (const float*)d_in[0];
  const float* Wc = (const float*)d_in[1];
  const float* bc = (const float*)d_in[2];
  const float* Wp = (const float*)d_in[3];
  const float* bp = (const float*)d_in[4];
  const float* sa = (const float*)d_in[5];
  const float* sb = (const float*)d_in[6];
  const float* Wo = (const float*)d_in[7];
  const float* bo = (const float*)d_in[8];
  float* out  = (float*)d_out;
  float* qbuf = (float*)d_ws;        // 77.1 MB; exports/y/proj reuse dead q channels
  float* Pbuf = out;                 // P (65536 f) + obp (512 f) in d_out scratch
  float* obpb = out + 65536;         // consumed by proj_k before out_k overwrites

  pe_k     <<<dim3(4),       dim3(256), 0, stream>>>(Wo, Wp, bp, Pbuf, obpb);
  q_conv   <<<dim3(64 * 49), dim3(128), 0, stream>>>(x, Wc, bc, qbuf);
  cluster_k<<<dim3(512),     dim3(512), 0, stream>>>(qbuf, sa, sb);
  seg_k    <<<dim3(512),     dim3(256), 0, stream>>>(qbuf, x);
  proj_k   <<<dim3(128),     dim3(256), 0, stream>>>(qbuf, Pbuf, obpb);
  out_k    <<<dim3(1792),    dim3(256), 0, stream>>>(qbuf, bo, out);
}